// Round 5
// baseline (286.614 us; speedup 1.0000x reference)
//
#include <hip/hip_runtime.h>
#include <hip/hip_bf16.h>

// A=8 agents, B=64 envs, S=1024 seq, H=128 hidden.
#define AN 8
#define BN 64
#define SN 1024
#define HN 128

typedef __attribute__((ext_vector_type(8))) short bf16x8;
typedef __attribute__((ext_vector_type(4))) float f32x4;

__device__ __forceinline__ unsigned short f2bf(float f) {
    unsigned u = __builtin_bit_cast(unsigned, f);
    return (unsigned short)((u + 0x7fffu + ((u >> 16) & 1u)) >> 16);  // RNE
}

// ---- pack kernel: W -> bf16 MFMA fragments + bias, into d_ws (33 KB) ----
// frag[e], e = nt*256 + ks*64 + l : lane l of tile (nt,ks) holds
// W[16*nt + (l&15)][32*ks + 8*(l>>4) + j], j=0..7  (layout verified R0-R3)
__global__ void pack_w(const float* __restrict__ W, const float* __restrict__ bias,
                       void* __restrict__ ws) {
    bf16x8* frag = (bf16x8*)ws;
    float*  bws  = (float*)((char*)ws + 2048 * 16);
    const int tid = threadIdx.x;
    for (int e = tid; e < 2048; e += 256) {
        int l  = e & 63;
        int ks = (e >> 6) & 3;
        int nt = e >> 8;
        int col = 16 * nt + (l & 15);
        int k0  = 32 * ks + 8 * (l >> 4);
        const float* wp = W + col * HN + k0;
        float4 w0 = *(const float4*)(wp);
        float4 w1 = *(const float4*)(wp + 4);
        bf16x8 f;
        f[0] = f2bf(w0.x); f[1] = f2bf(w0.y); f[2] = f2bf(w0.z); f[3] = f2bf(w0.w);
        f[4] = f2bf(w1.x); f[5] = f2bf(w1.y); f[6] = f2bf(w1.z); f[7] = f2bf(w1.w);
        frag[e] = f;
    }
    if (tid < HN) bws[tid] = bias[tid];
}

// ---- main kernel: zero LDS, zero barriers, deep load bursts ----
// Wave pair shares a 16-row strip; each wave computes 64 output cols (half).
__global__ __launch_bounds__(256, 5) void commnet_main(
    const float* __restrict__ obs,   // (A*B, S, H)
    const float* __restrict__ rnn,   // (S, B, A, H)
    const int*   __restrict__ alive, // (A, B, S, 1)
    const void*  __restrict__ ws,    // packed W frags + bias
    float* __restrict__ out)         // (A*B, S, H)
{
    const bf16x8* wfrag = (const bf16x8*)ws;
    const float*  bws   = (const float*)((const char*)ws + 2048 * 16);

    const int tid  = threadIdx.x;
    const int lane = tid & 63;
    const int wv   = tid >> 6;          // 0..3
    const int half = wv & 1;            // output-column half
    const int P    = blockIdx.x * 2 + (wv >> 1);   // pair id 0..8191
    const int ab   = P >> 4;            // 0..511 (4 strips per pair, ab-major)
    const int a    = ab >> 6;
    const int b    = ab & 63;
    const int sblk0 = (P & 15) * 4;     // strip block within (a,b)

    const int r  = lane & 15;           // strip row / msg col
    const int kg = lane >> 4;           // k-group / out col-group

    // loop-invariant bias (cols 64*half + 16*m + 4*kg + {0..3})
    float4 biv[4];
#pragma unroll
    for (int m = 0; m < 4; ++m)
        biv[m] = *(const float4*)(bws + 64 * half + 16 * m + 4 * kg);

    // alive scales for the pair's 4 strips (one burst, off the loop's path)
    float scales[4];
#pragma unroll
    for (int i = 0; i < 4; ++i) {
        const int s_r = ((sblk0 + i) << 4) + r;
        int asum = 0, mya = 0;
#pragma unroll
        for (int a2 = 0; a2 < AN; ++a2) {
            int v = alive[(a2 * BN + b) * SN + s_r];
            asum += v;
            if (a2 == a) mya = v;
        }
        scales[i] = mya ? 1.0f / (float)(asum < 1 ? 1 : asum) : 0.0f;
    }

#pragma unroll
    for (int i = 0; i < 4; ++i) {
        const int s_r = ((sblk0 + i) << 4) + r;

        // 8-deep rnn burst (independent, issued back-to-back)
        const float* arow = rnn + ((size_t)s_r * BN + b) * (AN * HN)
                                + a * HN + 8 * kg;
        float4 rv[8];
#pragma unroll
        for (int ks = 0; ks < 4; ++ks) {
            rv[2 * ks]     = *(const float4*)(arow + 32 * ks);
            rv[2 * ks + 1] = *(const float4*)(arow + 32 * ks + 4);
        }

        // 4-deep obs burst, issued before any dependent work
        const size_t obase = (size_t)(a * BN + b) * (SN * HN)
                           + (size_t)s_r * HN + 64 * half + 4 * kg;
        float4 ob[4];
#pragma unroll
        for (int m = 0; m < 4; ++m)
            ob[m] = *(const float4*)(obs + obase + 16 * m);

        // scale + convert to bf16 B-fragments
        const float sc = scales[i];
        bf16x8 mb[4];
#pragma unroll
        for (int ks = 0; ks < 4; ++ks) {
            float4 lo = rv[2 * ks], hi = rv[2 * ks + 1];
            mb[ks][0] = f2bf(lo.x * sc); mb[ks][1] = f2bf(lo.y * sc);
            mb[ks][2] = f2bf(lo.z * sc); mb[ks][3] = f2bf(lo.w * sc);
            mb[ks][4] = f2bf(hi.x * sc); mb[ks][5] = f2bf(hi.y * sc);
            mb[ks][6] = f2bf(hi.z * sc); mb[ks][7] = f2bf(hi.w * sc);
        }

        // MFMA; W-fragment loads from L1-hot ws. ks rotated by i so the
        // addresses are not loop-invariant (prevents 64-VGPR hoist).
        f32x4 acc[4];
#pragma unroll
        for (int m = 0; m < 4; ++m) acc[m] = (f32x4){0.f, 0.f, 0.f, 0.f};
#pragma unroll
        for (int kk = 0; kk < 4; ++kk) {
            const int ks = (kk + i) & 3;
#pragma unroll
            for (int m = 0; m < 4; ++m) {
                bf16x8 wf = wfrag[((4 * half + m) * 4 + ks) * 64 + lane];
                acc[m] = __builtin_amdgcn_mfma_f32_16x16x32_bf16(
                    wf, mb[ks], acc[m], 0, 0, 0);
            }
        }

        // epilogue: out = acc + bias + obs
#pragma unroll
        for (int m = 0; m < 4; ++m) {
            float4 res;
            res.x = acc[m][0] + biv[m].x + ob[m].x;
            res.y = acc[m][1] + biv[m].y + ob[m].y;
            res.z = acc[m][2] + biv[m].z + ob[m].z;
            res.w = acc[m][3] + biv[m].w + ob[m].w;
            *(float4*)(out + obase + 16 * m) = res;
        }
    }
}

extern "C" void kernel_launch(void* const* d_in, const int* in_sizes, int n_in,
                              void* d_out, int out_size, void* d_ws, size_t ws_size,
                              hipStream_t stream) {
    const float* obs   = (const float*)d_in[0];
    const float* rnn   = (const float*)d_in[1];
    const int*   alive = (const int*)d_in[2];
    const float* W     = (const float*)d_in[3];
    const float* bias  = (const float*)d_in[4];
    float* out = (float*)d_out;
    (void)in_sizes; (void)n_in; (void)ws_size; (void)out_size;

    pack_w<<<1, 256, 0, stream>>>(W, bias, d_ws);
    commnet_main<<<4096, 256, 0, stream>>>(obs, rnn, alive, d_ws, out);
}

// Round 6
// 182.975 us; speedup vs baseline: 1.5664x; 1.5664x over previous
//
#include <hip/hip_runtime.h>
#include <hip/hip_bf16.h>

// A=8 agents, B=64 envs, S=1024 seq, H=128 hidden.
#define AN 8
#define BN 64
#define SN 1024
#define HN 128
#define NSPB 16      // strips per block (one (a,b), s-window of 256)
#define NBLK 2048    // 512 ab * 4 s-chunks

typedef __attribute__((ext_vector_type(8))) short bf16x8;
typedef __attribute__((ext_vector_type(4))) float f32x4;

__device__ __forceinline__ unsigned short f2bf(float f) {
    unsigned u = __builtin_bit_cast(unsigned, f);
    return (unsigned short)((u + 0x7fffu + ((u >> 16) & 1u)) >> 16);  // RNE
}

__device__ __forceinline__ void gll16(const void* g, void* l) {
    __builtin_amdgcn_global_load_lds(
        (const __attribute__((address_space(1))) void*)g,
        (__attribute__((address_space(3))) void*)l, 16, 0, 0);
}

#define WAITV(n) asm volatile("s_waitcnt vmcnt(" #n ")" ::: "memory")
#define SCHED0() __builtin_amdgcn_sched_barrier(0)

// ---- pack kernel: W -> bf16 MFMA fragments + bias into d_ws (verified R4) ----
__global__ void pack_w(const float* __restrict__ W, const float* __restrict__ bias,
                       void* __restrict__ ws) {
    bf16x8* frag = (bf16x8*)ws;
    float*  bws  = (float*)((char*)ws + 2048 * 16);
    const int tid = threadIdx.x;
    for (int e = tid; e < 2048; e += 256) {
        int l  = e & 63;
        int ks = (e >> 6) & 3;
        int nt = e >> 8;
        int col = 16 * nt + (l & 15);
        int k0  = 32 * ks + 8 * (l >> 4);
        const float* wp = W + col * HN + k0;
        float4 w0 = *(const float4*)(wp);
        float4 w1 = *(const float4*)(wp + 4);
        bf16x8 f;
        f[0] = f2bf(w0.x); f[1] = f2bf(w0.y); f[2] = f2bf(w0.z); f[3] = f2bf(w0.w);
        f[4] = f2bf(w1.x); f[5] = f2bf(w1.y); f[6] = f2bf(w1.z); f[7] = f2bf(w1.w);
        frag[e] = f;
    }
    if (tid < HN) bws[tid] = bias[tid];
}

// Stage strip NEXT into LDS buffer BUF (per-wave share: 2 rnn gll + 2 obs gll).
// rnn: pre-swizzled global source -> linear LDS dest; swizzle granule:
// LDS_granule(row r, 16B-group q) = 32*r + (q ^ (r&7)).
#define STAGE(NEXT, BUF) do {                                                  \
    const int sb_ = s0base + ((NEXT) << 4);                                    \
    _Pragma("unroll")                                                          \
    for (int jj_ = 0; jj_ < 2; ++jj_) {                                        \
        const int j_   = 2 * wv + jj_;                                         \
        const int row_ = 2 * j_ + (lane >> 5);                                 \
        const int q_   = (lane & 31) ^ (row_ & 7);                             \
        const float* g_ = rnn + ((size_t)((sb_ + row_) * BN + b)) * (AN * HN)  \
                              + a * HN + 4 * q_;                               \
        gll16(g_, (void*)&rnn_lds[BUF][j_ * 256]);                             \
    }                                                                          \
    _Pragma("unroll")                                                          \
    for (int m_ = 0; m_ < 2; ++m_) {                                           \
        const float* g_ = obs + obsrow + (size_t)(sb_ + rr) * HN               \
                              + 16 * (2 * wv + m_) + 4 * kg;                   \
        gll16(g_, (void*)&obs_lds[wv][BUF][m_][0]);                            \
    }                                                                          \
} while (0)

// Process strip I from buffer BUF. PF = prefetch statement. WA/WB = literal
// vmcnt counts (steady: 6/4; last strip: 2/0). ENDBAR: trailing barrier.
#define BODY(I, BUF, PF, WA, WB, ENDBAR) do {                                  \
    const int strip_ = (I);                                                    \
    const int sb_ = s0base + (strip_ << 4);                                    \
    PF;                                                                        \
    WAITV(WA); SCHED0();                                                       \
    __builtin_amdgcn_s_barrier();                                              \
    const float sc_ = scale_lds[(strip_ << 4) | rr];                           \
    bf16x8 mb_[4];                                                             \
    _Pragma("unroll")                                                          \
    for (int ks_ = 0; ks_ < 4; ++ks_) {                                        \
        const int lin_ = rr * 512 + 128 * ks_ + 32 * kg;                       \
        const int swz_ = 16 * (rr & 7);                                        \
        f32x4 lo_ = *(const f32x4*)((const char*)&rnn_lds[BUF][0]              \
                                    + ((lin_ + 0) ^ swz_));                    \
        f32x4 hi_ = *(const f32x4*)((const char*)&rnn_lds[BUF][0]              \
                                    + ((lin_ + 16) ^ swz_));                   \
        mb_[ks_][0] = f2bf(lo_[0] * sc_); mb_[ks_][1] = f2bf(lo_[1] * sc_);    \
        mb_[ks_][2] = f2bf(lo_[2] * sc_); mb_[ks_][3] = f2bf(lo_[3] * sc_);    \
        mb_[ks_][4] = f2bf(hi_[0] * sc_); mb_[ks_][5] = f2bf(hi_[1] * sc_);    \
        mb_[ks_][6] = f2bf(hi_[2] * sc_); mb_[ks_][7] = f2bf(hi_[3] * sc_);    \
    }                                                                          \
    f32x4 acc0_ = (f32x4){0.f, 0.f, 0.f, 0.f};                                 \
    f32x4 acc1_ = (f32x4){0.f, 0.f, 0.f, 0.f};                                 \
    _Pragma("unroll")                                                          \
    for (int ks_ = 0; ks_ < 4; ++ks_) {                                        \
        acc0_ = __builtin_amdgcn_mfma_f32_16x16x32_bf16(wf[0][ks_], mb_[ks_],  \
                                                        acc0_, 0, 0, 0);       \
        acc1_ = __builtin_amdgcn_mfma_f32_16x16x32_bf16(wf[1][ks_], mb_[ks_],  \
                                                        acc1_, 0, 0, 0);       \
    }                                                                          \
    WAITV(WB); SCHED0();                                                       \
    f32x4 o0_ = *(const f32x4*)&obs_lds[wv][BUF][0][4 * lane];                 \
    f32x4 o1_ = *(const f32x4*)&obs_lds[wv][BUF][1][4 * lane];                 \
    const size_t ob_ = obsrow + (size_t)(sb_ + rr) * HN + 16 * (2 * wv) + 4 * kg; \
    float4 r0_, r1_;                                                           \
    r0_.x = acc0_[0] + biv[0].x + o0_[0]; r0_.y = acc0_[1] + biv[0].y + o0_[1];\
    r0_.z = acc0_[2] + biv[0].z + o0_[2]; r0_.w = acc0_[3] + biv[0].w + o0_[3];\
    r1_.x = acc1_[0] + biv[1].x + o1_[0]; r1_.y = acc1_[1] + biv[1].y + o1_[1];\
    r1_.z = acc1_[2] + biv[1].z + o1_[2]; r1_.w = acc1_[3] + biv[1].w + o1_[3];\
    *(float4*)(out + ob_)      = r0_;                                          \
    *(float4*)(out + ob_ + 16) = r1_;                                          \
    if (ENDBAR) __builtin_amdgcn_s_barrier();                                  \
} while (0)

__global__ __launch_bounds__(256) void commnet_main(
    const float* __restrict__ obs,   // (A*B, S, H)
    const float* __restrict__ rnn,   // (S, B, A, H)
    const int*   __restrict__ alive, // (A, B, S, 1)
    const void*  __restrict__ ws,    // packed W frags + bias
    float* __restrict__ out)         // (A*B, S, H)
{
    __shared__ float rnn_lds[2][2048];        // [buf][8KB], swizzled content
    __shared__ float obs_lds[4][2][2][256];   // [wave][buf][tile][1KB]
    __shared__ float scale_lds[NSPB * 16];

    const int tid  = threadIdx.x;
    const int lane = tid & 63;
    const int wv   = tid >> 6;        // 0..3, owns output cols 32*wv..+31
    const int rr   = lane & 15;       // strip row
    const int kg   = lane >> 4;       // k-group / out col-group

    const int bid    = blockIdx.x;
    const int ab     = bid >> 2;                 // 0..511
    const int a      = ab >> 6;
    const int b      = ab & 63;
    const int s0base = (bid & 3) << 8;           // s-chunk of 256
    const size_t obsrow = (size_t)(a * BN + b) * (SN * HN);

    // W fragments in registers: wf[m][ks] for tiles nt = 2*wv + m.
    const bf16x8* wsfrag = (const bf16x8*)ws;
    const float*  bws    = (const float*)((const char*)ws + 2048 * 16);
    bf16x8 wf[2][4];
#pragma unroll
    for (int m = 0; m < 2; ++m)
#pragma unroll
        for (int ks = 0; ks < 4; ++ks)
            wf[m][ks] = wsfrag[((2 * wv + m) * 4 + ks) * 64 + lane];
    float4 biv[2];
#pragma unroll
    for (int m = 0; m < 2; ++m)
        biv[m] = *(const float4*)(bws + 16 * (2 * wv + m) + 4 * kg);

    // alive scales for all 16 strips (one per thread)
    {
        const int st = tid >> 4, r2 = tid & 15;
        const int s_r = s0base + (st << 4) + r2;
        int asum = 0, mya = 0;
#pragma unroll
        for (int a2 = 0; a2 < AN; ++a2) {
            int v = alive[(a2 * BN + b) * SN + s_r];
            asum += v;
            if (a2 == a) mya = v;
        }
        scale_lds[tid] = mya ? 1.0f / (float)(asum < 1 ? 1 : asum) : 0.0f;
    }
    WAITV(0);
    __syncthreads();

    // pipeline: stage strip 0, then steady double-buffered loop
    STAGE(0, 0);
    for (int ii = 0; ii < 7; ++ii) {
        BODY(2 * ii,     0, STAGE(2 * ii + 1, 1), 6, 4, 1);
        BODY(2 * ii + 1, 1, STAGE(2 * ii + 2, 0), 6, 4, 1);
    }
    BODY(14, 0, STAGE(15, 1), 6, 4, 1);
    BODY(15, 1, (void)0, 2, 0, 0);
}

extern "C" void kernel_launch(void* const* d_in, const int* in_sizes, int n_in,
                              void* d_out, int out_size, void* d_ws, size_t ws_size,
                              hipStream_t stream) {
    const float* obs   = (const float*)d_in[0];
    const float* rnn   = (const float*)d_in[1];
    const int*   alive = (const int*)d_in[2];
    const float* W     = (const float*)d_in[3];
    const float* bias  = (const float*)d_in[4];
    float* out = (float*)d_out;
    (void)in_sizes; (void)n_in; (void)ws_size; (void)out_size;

    pack_w<<<1, 256, 0, stream>>>(W, bias, d_ws);
    commnet_main<<<NBLK, 256, 0, stream>>>(obs, rnn, alive, d_ws, out);
}